// Round 1
// baseline (57.441 us; speedup 1.0000x reference)
//
#include <hip/hip_runtime.h>
#include <math.h>

// ExpandFormerV15Complete: out = h + 0.1 * expert_corr(h) where each token
// belongs to at most ONE domain (member row is one-hot or zero).
// h = embed[x]  [B,S,64];  expert: 64 ->(W1[d])-> 128 -> GELU(exact) ->(W2[d])-> 64.
//
// One wave (64 lanes) per token. lane c owns h[c] and out[c].
//   matvec1: lane computes hid[2*lane], hid[2*lane+1]  (shfl-broadcast h, float2 W1 loads)
//   matvec2: lane computes corr[lane]                  (shfl-broadcast gelu(hid), coalesced W2 loads)

constexpr int BASE  = 64;
constexpr int HIDD  = 128;
constexpr int NDOM  = 8;
constexpr int NTOK  = 16 * 2048;
constexpr float CORR_SCALE = 0.1f;

__global__ __launch_bounds__(256) void expand_mlp_kernel(
    const int*   __restrict__ x,
    const float* __restrict__ embed,
    const float* __restrict__ W1,
    const float* __restrict__ W2,
    const float* __restrict__ member,
    float*       __restrict__ out)
{
    const int lane = threadIdx.x & 63;
    const int wave = threadIdx.x >> 6;
    const int tok  = blockIdx.x * 4 + wave;
    if (tok >= NTOK) return;

    const int id = x[tok];

    // gather h: 64 consecutive floats per token (256B coalesced per wave)
    const float hval = embed[(size_t)id * BASE + lane];

    // domain lookup: lanes 0..7 read the one-hot member row; wave-uniform result
    const float m = (lane < NDOM) ? member[(size_t)id * NDOM + lane] : 0.0f;
    const unsigned long long bal = __ballot(m > 0.5f);

    float result = hval;
    if (bal) {                       // wave-uniform branch
        const int d = (int)__builtin_ctzll(bal);

        // ---- matvec1: z[h] = sum_c h[c] * W1[d][c][h]; lane owns h = 2*lane, 2*lane+1
        const float2* __restrict__ w1p =
            (const float2*)(W1 + (size_t)d * BASE * HIDD);
        float z0 = 0.0f, z1 = 0.0f;
        #pragma unroll 16
        for (int c = 0; c < BASE; ++c) {
            const float  hc = __shfl(hval, c);                 // broadcast h[c]
            const float2 w  = w1p[c * (HIDD / 2) + lane];      // W1[d][c][2l], [2l+1]
            z0 = fmaf(hc, w.x, z0);
            z1 = fmaf(hc, w.y, z1);
        }

        // ---- exact GELU (reference uses approximate=False -> erf form)
        const float k = 0.70710678118654752f;                  // 1/sqrt(2)
        const float g0 = 0.5f * z0 * (1.0f + erff(z0 * k));
        const float g1 = 0.5f * z1 * (1.0f + erff(z1 * k));

        // ---- matvec2: corr[c] = sum_h gelu(z[h]) * W2[d][h][c]; lane owns c = lane
        const float* __restrict__ w2p = W2 + (size_t)d * HIDD * BASE;
        float acc = 0.0f;
        #pragma unroll 16
        for (int h2 = 0; h2 < HIDD / 2; ++h2) {
            const float a = __shfl(g0, h2);                    // hid[2*h2]
            const float b = __shfl(g1, h2);                    // hid[2*h2+1]
            acc = fmaf(a, w2p[(size_t)(2 * h2)     * BASE + lane], acc);
            acc = fmaf(b, w2p[(size_t)(2 * h2 + 1) * BASE + lane], acc);
        }
        result = fmaf(CORR_SCALE, acc, hval);
    }

    out[(size_t)tok * BASE + lane] = result;
}

extern "C" void kernel_launch(void* const* d_in, const int* in_sizes, int n_in,
                              void* d_out, int out_size, void* d_ws, size_t ws_size,
                              hipStream_t stream) {
    const int*   x      = (const int*)  d_in[0];
    const float* embed  = (const float*)d_in[1];
    const float* W1     = (const float*)d_in[2];
    const float* W2     = (const float*)d_in[3];
    const float* member = (const float*)d_in[4];
    float*       out    = (float*)d_out;

    const int blocks = NTOK / 4;  // 4 waves (tokens) per 256-thread block
    hipLaunchKernelGGL(expand_mlp_kernel, dim3(blocks), dim3(256), 0, stream,
                       x, embed, W1, W2, member, out);
}